// Round 2
// baseline (543.799 us; speedup 1.0000x reference)
//
#include <hip/hip_runtime.h>

using s8v = __attribute__((ext_vector_type(8))) short;
using s4v = __attribute__((ext_vector_type(4))) short;
using f4v = __attribute__((ext_vector_type(4))) float;
using bf8v = __attribute__((ext_vector_type(8))) __bf16;

__device__ __forceinline__ short f2b(float f) {
  __bf16 h = (__bf16)f;
  return __builtin_bit_cast(short, h);
}

__device__ __forceinline__ f4v mfma16(s8v a, s8v b, f4v c) {
  return __builtin_amdgcn_mfma_f32_16x16x32_bf16(
      __builtin_bit_cast(bf8v, a), __builtin_bit_cast(bf8v, b), c, 0, 0, 0);
}

__device__ __forceinline__ void glds16(const void* src, void* dst) {
  __builtin_amdgcn_global_load_lds(
      (const __attribute__((address_space(1))) void*)src,
      (__attribute__((address_space(3))) void*)dst, 16, 0, 0);
}

// ---------------------------------------------------------------- cast fp32->bf16
__global__ __launch_bounds__(256) void cast_kernel(
    const float* __restrict__ Q, const float* __restrict__ K,
    const float* __restrict__ Wq, const float* __restrict__ Wk,
    const float* __restrict__ Wv, const float* __restrict__ Wo,
    short* __restrict__ Qb, short* __restrict__ Kb,
    short* __restrict__ Wqb, short* __restrict__ Wkb,
    short* __restrict__ Wvb, short* __restrict__ Wob) {
  int bi = blockIdx.x;
  const float* src; short* dst; int off;
  if (bi < 2048)      { src = Q;  dst = Qb;  off = bi; }
  else if (bi < 4096) { src = K;  dst = Kb;  off = bi - 2048; }
  else if (bi < 4608) { src = Wq; dst = Wqb; off = bi - 4096; }
  else if (bi < 5120) { src = Wk; dst = Wkb; off = bi - 4608; }
  else if (bi < 5632) { src = Wv; dst = Wvb; off = bi - 5120; }
  else                { src = Wo; dst = Wob; off = bi - 5632; }
  size_t base = (size_t)off * 2048 + threadIdx.x * 8;
  f4v a = *(const f4v*)(src + base);
  f4v b = *(const f4v*)(src + base + 4);
  s8v o8;
#pragma unroll
  for (int j = 0; j < 4; ++j) { o8[j] = f2b(a[j]); o8[4 + j] = f2b(b[j]); }
  *(s8v*)(dst + base) = o8;
}

// ---------------------------------------------------------------- GEMM core
// C[128x128] = A[M,1024](bf16,K-major) x W[N,1024]^T (both K-major), K=1024, BK=64.
// LDS rows 64 shorts (128B), XOR-swizzled via pre-swizzled global source.
__device__ __forceinline__ void gemm_core(const short* __restrict__ A,
                                          const short* __restrict__ W,
                                          f4v acc[4][4], short* As, short* Ws,
                                          int tm, int tn, int tid) {
  const int lane = tid & 63, wid = tid >> 6;
  const int c = lane & 15, g = lane >> 4;
  const int wr = wid >> 1, wc = wid & 1;
  for (int kb = 0; kb < 16; ++kb) {
    __syncthreads();
#pragma unroll
    for (int p = 0; p < 4; ++p) {
      int row = p * 32 + wid * 8 + (lane >> 3);
      int chunk = (lane & 7) ^ (row & 7);
      glds16(A + (size_t)(tm + row) * 1024 + kb * 64 + chunk * 8,
             As + p * 2048 + wid * 512);
      glds16(W + (size_t)(tn + row) * 1024 + kb * 64 + chunk * 8,
             Ws + p * 2048 + wid * 512);
    }
    asm volatile("s_waitcnt vmcnt(0)" ::: "memory");
    __syncthreads();
#pragma unroll
    for (int ks = 0; ks < 2; ++ks) {
      s8v af[4], wf[4];
#pragma unroll
      for (int i = 0; i < 4; ++i) {
        int ra = wr * 64 + i * 16 + c;
        af[i] = *(const s8v*)(As + ra * 64 + ((((ks << 2) + g) ^ (ra & 7)) << 3));
        int rb = wc * 64 + i * 16 + c;
        wf[i] = *(const s8v*)(Ws + rb * 64 + ((((ks << 2) + g) ^ (rb & 7)) << 3));
      }
#pragma unroll
      for (int i = 0; i < 4; ++i)
#pragma unroll
        for (int j = 0; j < 4; ++j)
          acc[i][j] = mfma16(af[i], wf[j], acc[i][j]);
    }
  }
}

// ---------------------------------------------------------------- projection GEMMs
// z=0: q = Q@Wq^T+bq  -> fp32 [4096][1024]
// z=1: k = K@Wk^T+bk  -> bf16 [h][b][n][64]
// z=2: v = K@Wv^T+bv  -> bf16 [h][b][64][n]   (transposed within head)
__global__ __launch_bounds__(256, 2) void gemm_proj(
    const short* __restrict__ Qb, const short* __restrict__ Kb,
    const short* __restrict__ Wqb, const short* __restrict__ Wkb,
    const short* __restrict__ Wvb, const float* __restrict__ bq,
    const float* __restrict__ bk, const float* __restrict__ bv,
    float* __restrict__ qws, short* __restrict__ khs, short* __restrict__ vts) {
  __shared__ short As[8192], Ws[8192];
  const int tid = threadIdx.x, lane = tid & 63, wid = tid >> 6;
  const int c = lane & 15, g = lane >> 4;
  const int wr = wid >> 1, wc = wid & 1;
  const int tm = blockIdx.y * 128, tn = blockIdx.x * 128;
  const int z = blockIdx.z;
  const short* A = (z == 0) ? Qb : Kb;
  const short* W = (z == 0) ? Wqb : ((z == 1) ? Wkb : Wvb);
  const float* bias = (z == 0) ? bq : ((z == 1) ? bk : bv);
  f4v acc[4][4] = {};
  gemm_core(A, W, acc, As, Ws, tm, tn, tid);
#pragma unroll
  for (int j = 0; j < 4; ++j) {
    const int o = tn + wc * 64 + j * 16 + c;
    const float bj = bias[o];
    const int h = o >> 6, d = o & 63;
#pragma unroll
    for (int i = 0; i < 4; ++i) {
      const int m0 = tm + wr * 64 + i * 16 + g * 4;
      if (z == 0) {
#pragma unroll
        for (int r = 0; r < 4; ++r)
          qws[(size_t)(m0 + r) * 1024 + o] = acc[i][j][r] + bj;
      } else if (z == 1) {
        const int bidx = m0 >> 10;
#pragma unroll
        for (int r = 0; r < 4; ++r) {
          int n = (m0 + r) & 1023;
          khs[((size_t)(h * 4 + bidx) * 1024 + n) * 64 + d] =
              f2b(acc[i][j][r] + bj);
        }
      } else {
        const int bidx = m0 >> 10, n0 = m0 & 1023;
        s4v pk;
#pragma unroll
        for (int r = 0; r < 4; ++r) pk[r] = f2b(acc[i][j][r] + bj);
        *(s4v*)(vts + ((size_t)(h * 4 + bidx) * 64 + d) * 1024 + n0) = pk;
      }
    }
  }
}

// ---------------------------------------------------------------- output GEMM
// O2 = res + relu(t0b @ Wo^T + bo)
__global__ __launch_bounds__(256, 2) void gemm_out(
    const short* __restrict__ t0b, const short* __restrict__ Wob,
    const float* __restrict__ bo, const float* __restrict__ res,
    float* __restrict__ O2) {
  __shared__ short As[8192], Ws[8192];
  const int tid = threadIdx.x, lane = tid & 63, wid = tid >> 6;
  const int c = lane & 15, g = lane >> 4;
  const int wr = wid >> 1, wc = wid & 1;
  const int tm = blockIdx.y * 128, tn = blockIdx.x * 128;
  f4v acc[4][4] = {};
  gemm_core(t0b, Wob, acc, As, Ws, tm, tn, tid);
#pragma unroll
  for (int j = 0; j < 4; ++j) {
    const int o = tn + wc * 64 + j * 16 + c;
    const float bj = bo[o];
#pragma unroll
    for (int i = 0; i < 4; ++i) {
      const int m0 = tm + wr * 64 + i * 16 + g * 4;
#pragma unroll
      for (int r = 0; r < 4; ++r) {
        size_t idx = (size_t)(m0 + r) * 1024 + o;
        float y = acc[i][j][r] + bj;
        y = fmaxf(y, 0.f);
        O2[idx] = res[idx] + y;
      }
    }
  }
}

// ---------------------------------------------------------------- attention
// Per (hb, 128 q-rows). Transposed QK^T: St = mfma(Kfrag, Qfrag) so bias loads
// are contiguous f32x4 and column-softmax is in-register. P round-trips
// through per-wave LDS (stride 72 shorts) to form the PV A-fragment.
__global__ __launch_bounds__(256, 2) void attn_kernel(
    const short* __restrict__ khs, const short* __restrict__ vts,
    const float* __restrict__ qf, const float* __restrict__ sb,
    float* __restrict__ o_attn) {
  const int tid = threadIdx.x, wid = tid >> 6, lane = tid & 63;
  const int c = lane & 15, g = lane >> 4;
  const int hb = blockIdx.y, h = hb >> 2, b = hb & 3;
  const int qw = blockIdx.x * 128 + wid * 32;

  __shared__ short Ks[64 * 64];
  __shared__ short Vs[64 * 64];
  __shared__ short Ps[4 * 32 * 72];

  const short* kb_base = khs + (size_t)hb * 65536;    // [1024][64]
  const short* vb_base = vts + (size_t)hb * 65536;    // [64][1024]
  const float* sb_base = sb + (size_t)hb * 1048576;   // [1024][1024]

  // Q fragments (B-operand of St): q[qcol][d], 8 contiguous d, fp32->bf16
  s8v qb[2][2];
#pragma unroll
  for (int nf = 0; nf < 2; ++nf)
#pragma unroll
    for (int ks = 0; ks < 2; ++ks) {
      const float* qp = qf + ((size_t)(b * 1024 + qw + nf * 16 + c)) * 1024 +
                        h * 64 + ks * 32 + g * 8;
      f4v lo = *(const f4v*)qp;
      f4v hi = *(const f4v*)(qp + 4);
      s8v t;
#pragma unroll
      for (int j = 0; j < 4; ++j) { t[j] = f2b(lo[j]); t[4 + j] = f2b(hi[j]); }
      qb[nf][ks] = t;
    }

  float m_run[2] = {-3.0e38f, -3.0e38f};
  float l_run[2] = {0.f, 0.f};
  f4v oacc[2][4] = {};

  for (int kb = 0; kb < 16; ++kb) {
    __syncthreads();
#pragma unroll
    for (int p = 0; p < 2; ++p) {
      int row = p * 32 + wid * 8 + (lane >> 3);
      int chunk = (lane & 7) ^ (row & 7);
      glds16(kb_base + (size_t)(kb * 64 + row) * 64 + chunk * 8,
             Ks + p * 2048 + wid * 512);
      glds16(vb_base + (size_t)row * 1024 + kb * 64 + chunk * 8,
             Vs + p * 2048 + wid * 512);
    }
    asm volatile("s_waitcnt vmcnt(0)" ::: "memory");
    __syncthreads();

    // St = K·Q^T : rows = k-index (64), cols = q (32 per wave)
    f4v accs[4][2] = {};
#pragma unroll
    for (int ks = 0; ks < 2; ++ks) {
      s8v kf[4];
#pragma unroll
      for (int mf = 0; mf < 4; ++mf) {
        int row = mf * 16 + c;
        kf[mf] = *(const s8v*)(Ks + row * 64 +
                               ((((ks << 2) + g) ^ (row & 7)) << 3));
      }
#pragma unroll
      for (int mf = 0; mf < 4; ++mf)
#pragma unroll
        for (int nf = 0; nf < 2; ++nf)
          accs[mf][nf] = mfma16(kf[mf], qb[nf][ks], accs[mf][nf]);
    }

    // bias + online softmax (per q-column), write P (bf16) to per-wave LDS
    float alpha_s[2];
#pragma unroll
    for (int nf = 0; nf < 2; ++nf) {
      const int q = qw + nf * 16 + c;
      const float* bp0 = sb_base + (size_t)q * 1024 + kb * 64 + g * 4;
      float tmax = -3.0e38f;
#pragma unroll
      for (int mf = 0; mf < 4; ++mf) {
        f4v bb = *(const f4v*)(bp0 + mf * 16);
        f4v x = accs[mf][nf] * 0.03125f + bb;
        accs[mf][nf] = x;
        tmax = fmaxf(tmax, fmaxf(fmaxf(x[0], x[1]), fmaxf(x[2], x[3])));
      }
      tmax = fmaxf(tmax, __shfl_xor(tmax, 16));
      tmax = fmaxf(tmax, __shfl_xor(tmax, 32));
      const float mn = fmaxf(m_run[nf], tmax);
      const float al = __expf(m_run[nf] - mn);
      float ssum = 0.f;
#pragma unroll
      for (int mf = 0; mf < 4; ++mf) {
        f4v x = accs[mf][nf];
        float p0 = __expf(x[0] - mn), p1 = __expf(x[1] - mn);
        float p2 = __expf(x[2] - mn), p3 = __expf(x[3] - mn);
        ssum += (p0 + p1) + (p2 + p3);
        s4v pk;
        pk[0] = f2b(p0); pk[1] = f2b(p1); pk[2] = f2b(p2); pk[3] = f2b(p3);
        *(s4v*)(Ps + (size_t)wid * 2304 + (size_t)(nf * 16 + c) * 72 +
                mf * 16 + g * 4) = pk;
      }
      ssum += __shfl_xor(ssum, 16);
      ssum += __shfl_xor(ssum, 32);
      l_run[nf] = l_run[nf] * al + ssum;
      m_run[nf] = mn;
      alpha_s[nf] = al;
    }

    // rescale O accumulator (broadcast alpha from softmax-domain lanes)
#pragma unroll
    for (int mfq = 0; mfq < 2; ++mfq) {
      float a0 = __shfl(alpha_s[mfq], g * 4 + 0);
      float a1 = __shfl(alpha_s[mfq], g * 4 + 1);
      float a2 = __shfl(alpha_s[mfq], g * 4 + 2);
      float a3 = __shfl(alpha_s[mfq], g * 4 + 3);
#pragma unroll
      for (int nd = 0; nd < 4; ++nd) {
        oacc[mfq][nd][0] *= a0; oacc[mfq][nd][1] *= a1;
        oacc[mfq][nd][2] *= a2; oacc[mfq][nd][3] *= a3;
      }
    }

    // PV: O += P · V  (A-frag from Ps, B-frag from transposed V tile)
#pragma unroll
    for (int ks2 = 0; ks2 < 2; ++ks2) {
      s8v pf[2], vf[4];
#pragma unroll
      for (int mfq = 0; mfq < 2; ++mfq)
        pf[mfq] = *(const s8v*)(Ps + (size_t)wid * 2304 +
                                (size_t)(mfq * 16 + c) * 72 + ks2 * 32 + g * 8);
#pragma unroll
      for (int nd = 0; nd < 4; ++nd) {
        int d = nd * 16 + c;
        vf[nd] = *(const s8v*)(Vs + d * 64 +
                               ((((ks2 << 2) + g) ^ (d & 7)) << 3));
      }
#pragma unroll
      for (int mfq = 0; mfq < 2; ++mfq)
#pragma unroll
        for (int nd = 0; nd < 4; ++nd)
          oacc[mfq][nd] = mfma16(pf[mfq], vf[nd], oacc[mfq][nd]);
    }
  }

  // epilogue: O = q_residual + O/l
#pragma unroll
  for (int mfq = 0; mfq < 2; ++mfq) {
    float i0 = 1.f / __shfl(l_run[mfq], g * 4 + 0);
    float i1 = 1.f / __shfl(l_run[mfq], g * 4 + 1);
    float i2 = 1.f / __shfl(l_run[mfq], g * 4 + 2);
    float i3 = 1.f / __shfl(l_run[mfq], g * 4 + 3);
#pragma unroll
    for (int nd = 0; nd < 4; ++nd) {
      int d = nd * 16 + c;
      size_t base = ((size_t)(b * 1024 + qw + mfq * 16 + g * 4)) * 1024 +
                    h * 64 + d;
      o_attn[base]        = qf[base]        + oacc[mfq][nd][0] * i0;
      o_attn[base + 1024] = qf[base + 1024] + oacc[mfq][nd][1] * i1;
      o_attn[base + 2048] = qf[base + 2048] + oacc[mfq][nd][2] * i2;
      o_attn[base + 3072] = qf[base + 3072] + oacc[mfq][nd][3] * i3;
    }
  }
}

// ---------------------------------------------------------------- LayerNorm (row=1024)
template <bool WB>
__global__ __launch_bounds__(256) void ln_k(const float* __restrict__ in,
                                            float* __restrict__ out,
                                            short* __restrict__ outb,
                                            const float* __restrict__ gamma,
                                            const float* __restrict__ beta) {
  const int row = blockIdx.x, tid = threadIdx.x;
  const size_t base = (size_t)row * 1024 + tid * 4;
  f4v x = *(const f4v*)(in + base);
  float s = (x[0] + x[1]) + (x[2] + x[3]);
  float ss = (x[0] * x[0] + x[1] * x[1]) + (x[2] * x[2] + x[3] * x[3]);
#pragma unroll
  for (int m = 1; m < 64; m <<= 1) {
    s += __shfl_xor(s, m);
    ss += __shfl_xor(ss, m);
  }
  __shared__ float red[8];
  const int wid = tid >> 6, lane = tid & 63;
  if (lane == 0) { red[wid] = s; red[4 + wid] = ss; }
  __syncthreads();
  s = (red[0] + red[1]) + (red[2] + red[3]);
  ss = (red[4] + red[5]) + (red[6] + red[7]);
  const float mean = s * (1.f / 1024.f);
  const float var = ss * (1.f / 1024.f) - mean * mean;
  const float rs = rsqrtf(var + 1e-5f);
  const f4v gg = *(const f4v*)(gamma + tid * 4);
  const f4v bb = *(const f4v*)(beta + tid * 4);
  f4v y;
#pragma unroll
  for (int jj = 0; jj < 4; ++jj) y[jj] = (x[jj] - mean) * rs * gg[jj] + bb[jj];
  *(f4v*)(out + base) = y;
  if (WB) {
    s4v pk;
#pragma unroll
    for (int jj = 0; jj < 4; ++jj) pk[jj] = f2b(y[jj]);
    *(s4v*)(outb + base) = pk;
  }
}

// ---------------------------------------------------------------- launch
extern "C" void kernel_launch(void* const* d_in, const int* in_sizes, int n_in,
                              void* d_out, int out_size, void* d_ws,
                              size_t ws_size, hipStream_t stream) {
  const float* Q  = (const float*)d_in[0];
  const float* K  = (const float*)d_in[1];
  const float* sb = (const float*)d_in[2];
  const float* Wq = (const float*)d_in[3];
  const float* bq = (const float*)d_in[4];
  const float* Wk = (const float*)d_in[5];
  const float* bk = (const float*)d_in[6];
  const float* Wv = (const float*)d_in[7];
  const float* bv = (const float*)d_in[8];
  const float* Wo = (const float*)d_in[9];
  const float* bo = (const float*)d_in[10];
  const float* g0 = (const float*)d_in[11];
  const float* b0 = (const float*)d_in[12];
  const float* g1 = (const float*)d_in[13];
  const float* b1 = (const float*)d_in[14];
  float* out = (float*)d_out;

  char* ws = (char*)d_ws;
  size_t off = 0;
  auto alloc = [&](size_t bytes) -> void* {
    void* p = ws + off;
    off += (bytes + 255) & ~(size_t)255;
    return p;
  };
  float* qws  = (float*)alloc((size_t)16 << 20);  // q fp32 (reused as O2)
  short* khs  = (short*)alloc((size_t)8 << 20);   // K head-split bf16
  short* vts  = (short*)alloc((size_t)8 << 20);   // V head-split transposed bf16
  short* Qb   = (short*)alloc((size_t)8 << 20);
  short* Kb   = (short*)alloc((size_t)8 << 20);
  short* Wqb  = (short*)alloc((size_t)2 << 20);
  short* Wkb  = (short*)alloc((size_t)2 << 20);
  short* Wvb  = (short*)alloc((size_t)2 << 20);
  short* Wob  = (short*)alloc((size_t)2 << 20);
  float* oat  = (float*)alloc((size_t)16 << 20);  // attn out / t0 (in-place LN0)
  short* t0b  = (short*)alloc((size_t)8 << 20);
  float* O2   = qws;

  cast_kernel<<<6144, 256, 0, stream>>>(Q, K, Wq, Wk, Wv, Wo, Qb, Kb, Wqb, Wkb,
                                        Wvb, Wob);
  gemm_proj<<<dim3(8, 32, 3), 256, 0, stream>>>(Qb, Kb, Wqb, Wkb, Wvb, bq, bk,
                                                bv, qws, khs, vts);
  attn_kernel<<<dim3(8, 64), 256, 0, stream>>>(khs, vts, qws, sb, oat);
  ln_k<true><<<4096, 256, 0, stream>>>(oat, oat, t0b, g0, b0);
  gemm_out<<<dim3(8, 32), 256, 0, stream>>>(t0b, Wob, bo, oat, O2);
  ln_k<false><<<4096, 256, 0, stream>>>(O2, out, nullptr, g1, b1);
}

// Round 5
// 529.471 us; speedup vs baseline: 1.0271x; 1.0271x over previous
//
#include <hip/hip_runtime.h>

using s8v = __attribute__((ext_vector_type(8))) short;
using s4v = __attribute__((ext_vector_type(4))) short;
using f4v = __attribute__((ext_vector_type(4))) float;
using bf8v = __attribute__((ext_vector_type(8))) __bf16;

__device__ __forceinline__ short f2b(float f) {
  __bf16 h = (__bf16)f;
  return __builtin_bit_cast(short, h);
}

__device__ __forceinline__ f4v mfma16(s8v a, s8v b, f4v c) {
  return __builtin_amdgcn_mfma_f32_16x16x32_bf16(
      __builtin_bit_cast(bf8v, a), __builtin_bit_cast(bf8v, b), c, 0, 0, 0);
}

__device__ __forceinline__ void glds16(const void* src, void* dst) {
  __builtin_amdgcn_global_load_lds(
      (const __attribute__((address_space(1))) void*)src,
      (__attribute__((address_space(3))) void*)dst, 16, 0, 0);
}

// ---------------------------------------------------------------- cast fp32->bf16
__global__ __launch_bounds__(256) void cast_kernel(
    const float* __restrict__ Q, const float* __restrict__ K,
    const float* __restrict__ Wq, const float* __restrict__ Wk,
    const float* __restrict__ Wv, const float* __restrict__ Wo,
    short* __restrict__ Qb, short* __restrict__ Kb,
    short* __restrict__ Wqb, short* __restrict__ Wkb,
    short* __restrict__ Wvb, short* __restrict__ Wob) {
  int bi = blockIdx.x;
  const float* src; short* dst; int off;
  if (bi < 2048)      { src = Q;  dst = Qb;  off = bi; }
  else if (bi < 4096) { src = K;  dst = Kb;  off = bi - 2048; }
  else if (bi < 4608) { src = Wq; dst = Wqb; off = bi - 4096; }
  else if (bi < 5120) { src = Wk; dst = Wkb; off = bi - 4608; }
  else if (bi < 5632) { src = Wv; dst = Wvb; off = bi - 5120; }
  else                { src = Wo; dst = Wob; off = bi - 5632; }
  size_t base = (size_t)off * 2048 + threadIdx.x * 8;
  f4v a = *(const f4v*)(src + base);
  f4v b = *(const f4v*)(src + base + 4);
  s8v o8;
#pragma unroll
  for (int j = 0; j < 4; ++j) { o8[j] = f2b(a[j]); o8[4 + j] = f2b(b[j]); }
  *(s8v*)(dst + base) = o8;
}

// ---------------------------------------------------------------- GEMM core (dbuf)
// C[128x128] = A[M,1024] x W[N,1024]^T (both bf16 K-major), BK=64, 16 K-steps.
// Double-buffered LDS, 1 barrier/step: stage(next) -> MFMA(cur) -> drain+barrier.
__device__ __forceinline__ void stage_tile(const short* __restrict__ A,
                                           const short* __restrict__ W,
                                           short* As, short* Ws, int tm, int tn,
                                           int kb, int tid) {
  const int lane = tid & 63, wid = tid >> 6;
#pragma unroll
  for (int p = 0; p < 4; ++p) {
    int row = p * 32 + wid * 8 + (lane >> 3);
    int chunk = (lane & 7) ^ (row & 7);
    glds16(A + (size_t)(tm + row) * 1024 + kb * 64 + chunk * 8,
           As + p * 2048 + wid * 512);
    glds16(W + (size_t)(tn + row) * 1024 + kb * 64 + chunk * 8,
           Ws + p * 2048 + wid * 512);
  }
}

__device__ __forceinline__ void gemm_core_db(const short* __restrict__ A,
                                             const short* __restrict__ W,
                                             f4v acc[4][4], short* As, short* Ws,
                                             int tm, int tn, int tid) {
  const int lane = tid & 63, wid = tid >> 6;
  const int c = lane & 15, g = lane >> 4;
  const int wr = wid >> 1, wc = wid & 1;
  stage_tile(A, W, As, Ws, tm, tn, 0, tid);
  asm volatile("s_waitcnt vmcnt(0)" ::: "memory");
  __syncthreads();
  for (int kb = 0; kb < 16; ++kb) {
    const int cur = kb & 1;
    short* Asc = As + cur * 8192;
    short* Wsc = Ws + cur * 8192;
    if (kb < 15)
      stage_tile(A, W, As + (cur ^ 1) * 8192, Ws + (cur ^ 1) * 8192, tm, tn,
                 kb + 1, tid);
#pragma unroll
    for (int ks = 0; ks < 2; ++ks) {
      s8v af[4], wf[4];
#pragma unroll
      for (int i = 0; i < 4; ++i) {
        int ra = wr * 64 + i * 16 + c;
        af[i] = *(const s8v*)(Asc + ra * 64 + ((((ks << 2) + g) ^ (ra & 7)) << 3));
        int rb = wc * 64 + i * 16 + c;
        wf[i] = *(const s8v*)(Wsc + rb * 64 + ((((ks << 2) + g) ^ (rb & 7)) << 3));
      }
#pragma unroll
      for (int i = 0; i < 4; ++i)
#pragma unroll
        for (int j = 0; j < 4; ++j)
          acc[i][j] = mfma16(af[i], wf[j], acc[i][j]);
    }
    asm volatile("s_waitcnt vmcnt(0)" ::: "memory");
    __syncthreads();
  }
}

// XCD-aware remap for 8x32 = 256-block GEMM grids: XCD x owns 4 M-panels.
__device__ __forceinline__ void xcd_remap_gemm(int* tm, int* tn) {
  int d = blockIdx.y * 8 + blockIdx.x;
  int o = (d & 7) * 32 + (d >> 3);
  *tm = (o >> 3) * 128;
  *tn = (o & 7) * 128;
}

// ---------------------------------------------------------------- projection GEMMs
// z=0: q = Q@Wq^T+bq  -> fp32 [4096][1024]
// z=1: k = K@Wk^T+bk  -> bf16 [h][b][n][64]
// z=2: v = K@Wv^T+bv  -> bf16 [h][b][64][n]   (transposed within head)
__global__ __launch_bounds__(256, 2) void gemm_proj(
    const short* __restrict__ Qb, const short* __restrict__ Kb,
    const short* __restrict__ Wqb, const short* __restrict__ Wkb,
    const short* __restrict__ Wvb, const float* __restrict__ bq,
    const float* __restrict__ bk, const float* __restrict__ bv,
    float* __restrict__ qws, short* __restrict__ khs, short* __restrict__ vts) {
  __shared__ short As[16384], Ws[16384];
  const int tid = threadIdx.x, lane = tid & 63, wid = tid >> 6;
  const int c = lane & 15, g = lane >> 4;
  const int wr = wid >> 1, wc = wid & 1;
  int tm, tn;
  xcd_remap_gemm(&tm, &tn);
  const int z = blockIdx.z;
  const short* A = (z == 0) ? Qb : Kb;
  const short* W = (z == 0) ? Wqb : ((z == 1) ? Wkb : Wvb);
  const float* bias = (z == 0) ? bq : ((z == 1) ? bk : bv);
  f4v acc[4][4] = {};
  gemm_core_db(A, W, acc, As, Ws, tm, tn, tid);
#pragma unroll
  for (int j = 0; j < 4; ++j) {
    const int o = tn + wc * 64 + j * 16 + c;
    const float bj = bias[o];
    const int h = o >> 6, d = o & 63;
#pragma unroll
    for (int i = 0; i < 4; ++i) {
      const int m0 = tm + wr * 64 + i * 16 + g * 4;
      if (z == 0) {
#pragma unroll
        for (int r = 0; r < 4; ++r)
          qws[(size_t)(m0 + r) * 1024 + o] = acc[i][j][r] + bj;
      } else if (z == 1) {
        const int bidx = m0 >> 10;
#pragma unroll
        for (int r = 0; r < 4; ++r) {
          int n = (m0 + r) & 1023;
          khs[((size_t)(h * 4 + bidx) * 1024 + n) * 64 + d] =
              f2b(acc[i][j][r] + bj);
        }
      } else {
        const int bidx = m0 >> 10, n0 = m0 & 1023;
        s4v pk;
#pragma unroll
        for (int r = 0; r < 4; ++r) pk[r] = f2b(acc[i][j][r] + bj);
        *(s4v*)(vts + ((size_t)(h * 4 + bidx) * 64 + d) * 1024 + n0) = pk;
      }
    }
  }
}

// ---------------------------------------------------------------- output GEMM
// O2 = res + relu(t0b @ Wo^T + bo)
__global__ __launch_bounds__(256, 2) void gemm_out(
    const short* __restrict__ t0b, const short* __restrict__ Wob,
    const float* __restrict__ bo, const float* __restrict__ res,
    float* __restrict__ O2) {
  __shared__ short As[16384], Ws[16384];
  const int tid = threadIdx.x, lane = tid & 63, wid = tid >> 6;
  const int c = lane & 15, g = lane >> 4;
  const int wr = wid >> 1, wc = wid & 1;
  int tm, tn;
  xcd_remap_gemm(&tm, &tn);
  f4v acc[4][4] = {};
  gemm_core_db(t0b, Wob, acc, As, Ws, tm, tn, tid);
#pragma unroll
  for (int j = 0; j < 4; ++j) {
    const int o = tn + wc * 64 + j * 16 + c;
    const float bj = bo[o];
#pragma unroll
    for (int i = 0; i < 4; ++i) {
      const int m0 = tm + wr * 64 + i * 16 + g * 4;
#pragma unroll
      for (int r = 0; r < 4; ++r) {
        size_t idx = (size_t)(m0 + r) * 1024 + o;
        float y = acc[i][j][r] + bj;
        y = fmaxf(y, 0.f);
        O2[idx] = res[idx] + y;
      }
    }
  }
}

// ---------------------------------------------------------------- attention
// Per (hb, 128 q-rows). Transposed QK^T: St = mfma(Kfrag, Qfrag). Dbuf K/V LDS
// (1 barrier/step); bias prefetched one kb-step ahead into VGPRs.
__global__ __launch_bounds__(256, 2) void attn_kernel(
    const short* __restrict__ khs, const short* __restrict__ vts,
    const float* __restrict__ qf, const float* __restrict__ sb,
    float* __restrict__ o_attn) {
  const int tid = threadIdx.x, wid = tid >> 6, lane = tid & 63;
  const int c = lane & 15, g = lane >> 4;
  // XCD remap: each XCD owns 8 consecutive hb (K/V stays in its L2)
  const int dlin = blockIdx.y * 8 + blockIdx.x;
  const int o = (dlin & 7) * 64 + (dlin >> 3);
  const int hb = o >> 3, h = hb >> 2, b = hb & 3;
  const int qw = (o & 7) * 128 + wid * 32;

  __shared__ short Ks[2 * 4096];
  __shared__ short Vs[2 * 4096];
  __shared__ short Ps[4 * 32 * 72];

  const short* kb_base = khs + (size_t)hb * 65536;    // [1024][64]
  const short* vb_base = vts + (size_t)hb * 65536;    // [64][1024]
  const float* sb_base = sb + (size_t)hb * 1048576;   // [1024][1024]

  // Q fragments (B-operand of St)
  s8v qb[2][2];
#pragma unroll
  for (int nf = 0; nf < 2; ++nf)
#pragma unroll
    for (int ks = 0; ks < 2; ++ks) {
      const float* qp = qf + ((size_t)(b * 1024 + qw + nf * 16 + c)) * 1024 +
                        h * 64 + ks * 32 + g * 8;
      f4v lo = *(const f4v*)qp;
      f4v hi = *(const f4v*)(qp + 4);
      s8v t;
#pragma unroll
      for (int j = 0; j < 4; ++j) { t[j] = f2b(lo[j]); t[4 + j] = f2b(hi[j]); }
      qb[nf][ks] = t;
    }

  auto stage_kv = [&](int buf, int kb) {
#pragma unroll
    for (int p = 0; p < 2; ++p) {
      int row = p * 32 + wid * 8 + (lane >> 3);
      int chunk = (lane & 7) ^ (row & 7);
      glds16(kb_base + (size_t)(kb * 64 + row) * 64 + chunk * 8,
             Ks + buf * 4096 + p * 2048 + wid * 512);
      glds16(vb_base + (size_t)row * 1024 + kb * 64 + chunk * 8,
             Vs + buf * 4096 + p * 2048 + wid * 512);
    }
  };

  float m_run[2] = {-3.0e38f, -3.0e38f};
  float l_run[2] = {0.f, 0.f};
  f4v oacc[2][4] = {};

  // prologue: stage kb=0, prefetch bias kb=0
  stage_kv(0, 0);
  f4v bc[2][4];
#pragma unroll
  for (int nf = 0; nf < 2; ++nf) {
    const float* bp0 =
        sb_base + (size_t)(qw + nf * 16 + c) * 1024 + g * 4;
#pragma unroll
    for (int mf = 0; mf < 4; ++mf) bc[nf][mf] = *(const f4v*)(bp0 + mf * 16);
  }
  asm volatile("s_waitcnt vmcnt(0)" ::: "memory");
  __syncthreads();

  for (int kb = 0; kb < 16; ++kb) {
    const int cur = kb & 1;
    const short* Ksc = Ks + cur * 4096;
    const short* Vsc = Vs + cur * 4096;
    // stage next K/V tile + prefetch next bias (consumed next iteration)
    if (kb < 15) stage_kv(cur ^ 1, kb + 1);
    f4v bn[2][4];
    if (kb < 15) {
#pragma unroll
      for (int nf = 0; nf < 2; ++nf) {
        const float* bp0 = sb_base + (size_t)(qw + nf * 16 + c) * 1024 +
                           (kb + 1) * 64 + g * 4;
#pragma unroll
        for (int mf = 0; mf < 4; ++mf) bn[nf][mf] = *(const f4v*)(bp0 + mf * 16);
      }
    }

    // St = K·Q^T : rows = k-index (64), cols = q (32 per wave)
    f4v accs[4][2] = {};
#pragma unroll
    for (int ks = 0; ks < 2; ++ks) {
      s8v kf[4];
#pragma unroll
      for (int mf = 0; mf < 4; ++mf) {
        int row = mf * 16 + c;
        kf[mf] = *(const s8v*)(Ksc + row * 64 +
                               ((((ks << 2) + g) ^ (row & 7)) << 3));
      }
#pragma unroll
      for (int mf = 0; mf < 4; ++mf)
#pragma unroll
        for (int nf = 0; nf < 2; ++nf)
          accs[mf][nf] = mfma16(kf[mf], qb[nf][ks], accs[mf][nf]);
    }

    // bias + online softmax (per q-column), write P (bf16) to per-wave LDS
    float alpha_s[2];
#pragma unroll
    for (int nf = 0; nf < 2; ++nf) {
      float tmax = -3.0e38f;
#pragma unroll
      for (int mf = 0; mf < 4; ++mf) {
        f4v x = accs[mf][nf] * 0.03125f + bc[nf][mf];
        accs[mf][nf] = x;
        tmax = fmaxf(tmax, fmaxf(fmaxf(x[0], x[1]), fmaxf(x[2], x[3])));
      }
      tmax = fmaxf(tmax, __shfl_xor(tmax, 16));
      tmax = fmaxf(tmax, __shfl_xor(tmax, 32));
      const float mn = fmaxf(m_run[nf], tmax);
      const float al = __expf(m_run[nf] - mn);
      float ssum = 0.f;
#pragma unroll
      for (int mf = 0; mf < 4; ++mf) {
        f4v x = accs[mf][nf];
        float p0 = __expf(x[0] - mn), p1 = __expf(x[1] - mn);
        float p2 = __expf(x[2] - mn), p3 = __expf(x[3] - mn);
        ssum += (p0 + p1) + (p2 + p3);
        s4v pk;
        pk[0] = f2b(p0); pk[1] = f2b(p1); pk[2] = f2b(p2); pk[3] = f2b(p3);
        *(s4v*)(Ps + (size_t)wid * 2304 + (size_t)(nf * 16 + c) * 72 +
                mf * 16 + g * 4) = pk;
      }
      ssum += __shfl_xor(ssum, 16);
      ssum += __shfl_xor(ssum, 32);
      l_run[nf] = l_run[nf] * al + ssum;
      m_run[nf] = mn;
      alpha_s[nf] = al;
    }

    // rescale O accumulator
#pragma unroll
    for (int mfq = 0; mfq < 2; ++mfq) {
      float a0 = __shfl(alpha_s[mfq], g * 4 + 0);
      float a1 = __shfl(alpha_s[mfq], g * 4 + 1);
      float a2 = __shfl(alpha_s[mfq], g * 4 + 2);
      float a3 = __shfl(alpha_s[mfq], g * 4 + 3);
#pragma unroll
      for (int nd = 0; nd < 4; ++nd) {
        oacc[mfq][nd][0] *= a0; oacc[mfq][nd][1] *= a1;
        oacc[mfq][nd][2] *= a2; oacc[mfq][nd][3] *= a3;
      }
    }

    // PV: O += P · V
#pragma unroll
    for (int ks2 = 0; ks2 < 2; ++ks2) {
      s8v pf[2], vf[4];
#pragma unroll
      for (int mfq = 0; mfq < 2; ++mfq)
        pf[mfq] = *(const s8v*)(Ps + (size_t)wid * 2304 +
                                (size_t)(mfq * 16 + c) * 72 + ks2 * 32 + g * 8);
#pragma unroll
      for (int nd = 0; nd < 4; ++nd) {
        int d = nd * 16 + c;
        vf[nd] = *(const s8v*)(Vsc + d * 64 +
                               ((((ks2 << 2) + g) ^ (d & 7)) << 3));
      }
#pragma unroll
      for (int mfq = 0; mfq < 2; ++mfq)
#pragma unroll
        for (int nd = 0; nd < 4; ++nd)
          oacc[mfq][nd] = mfma16(pf[mfq], vf[nd], oacc[mfq][nd]);
    }

    asm volatile("s_waitcnt vmcnt(0)" ::: "memory");
    __syncthreads();
    if (kb < 15) {
#pragma unroll
      for (int nf = 0; nf < 2; ++nf)
#pragma unroll
        for (int mf = 0; mf < 4; ++mf) bc[nf][mf] = bn[nf][mf];
    }
  }

  // epilogue: O = q_residual + O/l
#pragma unroll
  for (int mfq = 0; mfq < 2; ++mfq) {
    float i0 = 1.f / __shfl(l_run[mfq], g * 4 + 0);
    float i1 = 1.f / __shfl(l_run[mfq], g * 4 + 1);
    float i2 = 1.f / __shfl(l_run[mfq], g * 4 + 2);
    float i3 = 1.f / __shfl(l_run[mfq], g * 4 + 3);
#pragma unroll
    for (int nd = 0; nd < 4; ++nd) {
      int d = nd * 16 + c;
      size_t base = ((size_t)(b * 1024 + qw + mfq * 16 + g * 4)) * 1024 +
                    h * 64 + d;
      o_attn[base]        = qf[base]        + oacc[mfq][nd][0] * i0;
      o_attn[base + 1024] = qf[base + 1024] + oacc[mfq][nd][1] * i1;
      o_attn[base + 2048] = qf[base + 2048] + oacc[mfq][nd][2] * i2;
      o_attn[base + 3072] = qf[base + 3072] + oacc[mfq][nd][3] * i3;
    }
  }
}

// ---------------------------------------------------------------- LayerNorm (row=1024)
template <bool WB>
__global__ __launch_bounds__(256) void ln_k(const float* __restrict__ in,
                                            float* __restrict__ out,
                                            short* __restrict__ outb,
                                            const float* __restrict__ gamma,
                                            const float* __restrict__ beta) {
  const int row = blockIdx.x, tid = threadIdx.x;
  const size_t base = (size_t)row * 1024 + tid * 4;
  f4v x = *(const f4v*)(in + base);
  float s = (x[0] + x[1]) + (x[2] + x[3]);
  float ss = (x[0] * x[0] + x[1] * x[1]) + (x[2] * x[2] + x[3] * x[3]);
#pragma unroll
  for (int m = 1; m < 64; m <<= 1) {
    s += __shfl_xor(s, m);
    ss += __shfl_xor(ss, m);
  }
  __shared__ float red[8];
  const int wid = tid >> 6, lane = tid & 63;
  if (lane == 0) { red[wid] = s; red[4 + wid] = ss; }
  __syncthreads();
  s = (red[0] + red[1]) + (red[2] + red[3]);
  ss = (red[4] + red[5]) + (red[6] + red[7]);
  const float mean = s * (1.f / 1024.f);
  const float var = ss * (1.f / 1024.f) - mean * mean;
  const float rs = rsqrtf(var + 1e-5f);
  const f4v gg = *(const f4v*)(gamma + tid * 4);
  const f4v bb = *(const f4v*)(beta + tid * 4);
  f4v y;
#pragma unroll
  for (int jj = 0; jj < 4; ++jj) y[jj] = (x[jj] - mean) * rs * gg[jj] + bb[jj];
  *(f4v*)(out + base) = y;
  if (WB) {
    s4v pk;
#pragma unroll
    for (int jj = 0; jj < 4; ++jj) pk[jj] = f2b(y[jj]);
    *(s4v*)(outb + base) = pk;
  }
}

// ---------------------------------------------------------------- launch
extern "C" void kernel_launch(void* const* d_in, const int* in_sizes, int n_in,
                              void* d_out, int out_size, void* d_ws,
                              size_t ws_size, hipStream_t stream) {
  const float* Q  = (const float*)d_in[0];
  const float* K  = (const float*)d_in[1];
  const float* sb = (const float*)d_in[2];
  const float* Wq = (const float*)d_in[3];
  const float* bq = (const float*)d_in[4];
  const float* Wk = (const float*)d_in[5];
  const float* bk = (const float*)d_in[6];
  const float* Wv = (const float*)d_in[7];
  const float* bv = (const float*)d_in[8];
  const float* Wo = (const float*)d_in[9];
  const float* bo = (const float*)d_in[10];
  const float* g0 = (const float*)d_in[11];
  const float* b0 = (const float*)d_in[12];
  const float* g1 = (const float*)d_in[13];
  const float* b1 = (const float*)d_in[14];
  float* out = (float*)d_out;

  char* ws = (char*)d_ws;
  size_t off = 0;
  auto alloc = [&](size_t bytes) -> void* {
    void* p = ws + off;
    off += (bytes + 255) & ~(size_t)255;
    return p;
  };
  float* qws  = (float*)alloc((size_t)16 << 20);  // q fp32 (reused as O2)
  short* khs  = (short*)alloc((size_t)8 << 20);   // K head-split bf16
  short* vts  = (short*)alloc((size_t)8 << 20);   // V head-split transposed bf16
  short* Qb   = (short*)alloc((size_t)8 << 20);
  short* Kb   = (short*)alloc((size_t)8 << 20);
  short* Wqb  = (short*)alloc((size_t)2 << 20);
  short* Wkb  = (short*)alloc((size_t)2 << 20);
  short* Wvb  = (short*)alloc((size_t)2 << 20);
  short* Wob  = (short*)alloc((size_t)2 << 20);
  float* oat  = (float*)alloc((size_t)16 << 20);  // attn out / t0 (in-place LN0)
  short* t0b  = (short*)alloc((size_t)8 << 20);
  float* O2   = qws;

  cast_kernel<<<6144, 256, 0, stream>>>(Q, K, Wq, Wk, Wv, Wo, Qb, Kb, Wqb, Wkb,
                                        Wvb, Wob);
  gemm_proj<<<dim3(8, 32, 3), 256, 0, stream>>>(Qb, Kb, Wqb, Wkb, Wvb, bq, bk,
                                                bv, qws, khs, vts);
  attn_kernel<<<dim3(8, 64), 256, 0, stream>>>(khs, vts, qws, sb, oat);
  ln_k<true><<<4096, 256, 0, stream>>>(oat, oat, t0b, g0, b0);
  gemm_out<<<dim3(8, 32), 256, 0, stream>>>(t0b, Wob, bo, oat, O2);
  ln_k<false><<<4096, 256, 0, stream>>>(O2, out, nullptr, g1, b1);
}